// Round 15
// baseline (342.397 us; speedup 1.0000x reference)
//
#include <hip/hip_runtime.h>

// ABLATION ROUND: three co-compiled variants of the v7 shift-GEMM skeleton.
//  MODE 0: drain-free barrier (builtin s_waitcnt lgkmcnt-only + raw s_barrier)
//  MODE 1: gathers always from shift-0 window (L2-hot) + full __syncthreads
//  MODE 2: v7 unmodified (correct) -- runs LAST, owns final d_out
// Per-dispatch rocprof rows give the marginal cost of (a) the vmcnt(0) drain,
// (b) gather-return latency. Headline dur is sacrificial this round.

typedef __attribute__((ext_vector_type(8)))  _Float16 f16x8;
typedef __attribute__((ext_vector_type(16))) float    f32x16;

struct __attribute__((aligned(4))) f2u { float x, y; };

constexpr int C_IN = 64, H = 112, W = 112;
constexpr int COUT = 128, OH = 110, OW = 110;
constexpr int NIMG = 32;
constexpr int KTOT = C_IN * 9;            // 576
constexpr int OSP  = OH * OW;             // 12100
constexpr int SPTOT = NIMG * OSP;         // 387200 = 3025*128
constexpr int IMG_STRIDE = C_IN * H * W;
constexpr int CH_STRIDE  = H * W;         // 12544
constexpr int LDC = 72;                   // hw per sp-row (144B, 16B-aligned)

__device__ __forceinline__ uint pkrtz_u32(float lo, float hi) {
    union { __fp16 __attribute__((ext_vector_type(2))) h; uint u; } c;
    c.h = __builtin_amdgcn_cvt_pkrtz(lo, hi);
    return c.u;
}

__device__ __forceinline__ int swz(int row, int chw) {
    return row * LDC + (chw ^ (((row >> 1) & 7) << 3));
}

// A16[((s*8+o)*COUT + cout)*8 + j] = (f16)Kw[cout][(o*8+j)*9 + s]  (v4-verified)
__global__ void prep_a(const float* __restrict__ Kw, _Float16* __restrict__ A16) {
    int idx = blockIdx.x * 256 + threadIdx.x;
    if (idx >= COUT * KTOT) return;
    int cout = idx / KTOT, k = idx - cout * KTOT;
    int c = k / 9, s = k - c * 9;
    int o = c >> 3, j = c & 7;
    A16[((size_t)(s * 8 + o) * COUT + cout) * 8 + j] = (_Float16)Kw[idx];
}

template <int MODE>
__global__ __launch_bounds__(512, 4)
void conv_abl(const float* __restrict__ X,
              const _Float16* __restrict__ A16,
              float* __restrict__ Out)
{
    __shared__ __align__(16) _Float16 Bs[2][128 * LDC];   // 36864 B

    const int t = threadIdx.x;

    const int nwg = gridDim.x;
    const int q8 = nwg >> 3, r8 = nwg & 7;
    const int xcd = blockIdx.x & 7, idx8 = blockIdx.x >> 3;
    const int bid = (xcd < r8 ? xcd * (q8 + 1) : r8 * (q8 + 1) + (xcd - r8) * q8) + idx8;
    const int spBase = bid * 128;

    // ---- staging mapping (v4-identical) ----
    const int spp = t & 63;
    const int c0  = (t >> 6) << 3;
    const int sp0 = spBase + 2 * spp;
    const int nimg = sp0 / OSP;
    const int rsp  = sp0 - nimg * OSP;
    const int oh   = rsp / OW;
    const int ow   = rsp - oh * OW;
    const float* Xr = X + ((size_t)nimg * IMG_STRIDE + (size_t)c0 * CH_STRIDE + oh * W + ow);
    const int whw0 = swz(2 * spp,     c0);
    const int whw1 = swz(2 * spp + 1, c0);

    // ---- compute mapping (v4-identical): 8 waves = 4 cout-q x 2 sp-halves ----
    const int lane  = t & 63;
    const int wv    = t >> 6;
    const int wq    = wv >> 1;
    const int wc    = wv & 1;
    const int frow  = lane & 31;
    const int khalf = lane >> 5;
    const size_t arow = (size_t)(wq * 32 + frow) * 8;
    const int bmask = ((frow >> 1) & 7) << 3;
    const int brw0  = (wc * 64 + frow) * LDC;
    const int brw1  = (wc * 64 + 32 + frow) * LDC;

    f32x16 acc[2];
#pragma unroll
    for (int j = 0; j < 2; j++)
#pragma unroll
        for (int e = 0; e < 16; e++) acc[j][e] = 0.f;

    f2u g[8];
    f16x8 aA[4], aB[4];

    // MODE 1: hot window -- every step re-reads shift-0 addresses (L2-hit)
#define SOFF(S) ((MODE == 1) ? 0 : ((((S) / 3) * W) + ((S) % 3)))

#define BAR()                                                                  \
    {                                                                          \
        if (MODE == 0) {                                                       \
            __builtin_amdgcn_s_waitcnt(0xC07F); /* lgkmcnt(0) only */          \
            __builtin_amdgcn_s_barrier();                                      \
        } else {                                                               \
            __syncthreads();                                                   \
        }                                                                      \
    }

#define GATHER(S)                                                              \
    {                                                                          \
        _Pragma("unroll")                                                      \
        for (int j = 0; j < 8; j++)                                            \
            g[j] = *reinterpret_cast<const f2u*>(Xr + (size_t)j * CH_STRIDE + SOFF(S)); \
    }

#define CVTWRITE(BUF)                                                          \
    {                                                                          \
        union { uint u[4]; f16x8 v; } px, py;                                  \
        _Pragma("unroll")                                                      \
        for (int p = 0; p < 4; p++) {                                          \
            px.u[p] = pkrtz_u32(g[2 * p].x, g[2 * p + 1].x);                   \
            py.u[p] = pkrtz_u32(g[2 * p].y, g[2 * p + 1].y);                   \
        }                                                                      \
        *reinterpret_cast<f16x8*>(&Bs[BUF][whw0]) = px.v;                      \
        *reinterpret_cast<f16x8*>(&Bs[BUF][whw1]) = py.v;                      \
    }

#define ALOAD(DST, S)                                                          \
    {                                                                          \
        _Pragma("unroll")                                                      \
        for (int kk = 0; kk < 4; kk++)                                         \
            DST[kk] = *reinterpret_cast<const f16x8*>(                         \
                &A16[(size_t)(((S) * 8 + kk * 2 + khalf) * COUT) * 8 + arow]); \
    }

#define MFMA_STEP(B, AREG)                                                     \
    {                                                                          \
        _Pragma("unroll")                                                      \
        for (int kk = 0; kk < 4; kk++) {                                       \
            const int chw = (kk * 16 + khalf * 8) ^ bmask;                     \
            f16x8 b0 = *reinterpret_cast<const f16x8*>(&Bs[B][brw0 + chw]);    \
            f16x8 b1 = *reinterpret_cast<const f16x8*>(&Bs[B][brw1 + chw]);    \
            acc[0] = __builtin_amdgcn_mfma_f32_32x32x16_f16(AREG[kk], b0, acc[0], 0, 0, 0); \
            acc[1] = __builtin_amdgcn_mfma_f32_32x32x16_f16(AREG[kk], b1, acc[1], 0, 0, 0); \
        }                                                                      \
    }

#define STEP(S, CUR, NXT)                                                      \
    {                                                                          \
        ALOAD(NXT, (S) + 1);                                                   \
        CVTWRITE(((S) + 1) & 1);                                               \
        if ((S) < 7) GATHER((S) + 2);                                          \
        MFMA_STEP((S) & 1, CUR);                                               \
        BAR();                                                                 \
    }

    // ---- prologue ----
    ALOAD(aA, 0);
    GATHER(0);
    CVTWRITE(0);
    GATHER(1);
    BAR();

    STEP(0, aA, aB);
    STEP(1, aB, aA);
    STEP(2, aA, aB);
    STEP(3, aB, aA);
    STEP(4, aA, aB);
    STEP(5, aB, aA);
    STEP(6, aA, aB);
    STEP(7, aB, aA);
    MFMA_STEP(0, aA);   // s=8

#undef GATHER
#undef CVTWRITE
#undef ALOAD
#undef MFMA_STEP
#undef STEP
#undef SOFF
#undef BAR

    // ---- store (v3-verified) ----
#pragma unroll
    for (int j = 0; j < 2; j++) {
        const int sp2 = spBase + wc * 64 + j * 32 + frow;
        const int n2  = sp2 / OSP;
        const int r2  = sp2 - n2 * OSP;
        float* Ob = Out + (size_t)n2 * (COUT * (size_t)OSP) + r2;
        const int cbase = wq * 32 + 4 * khalf;
#pragma unroll
        for (int reg = 0; reg < 16; reg++) {
            const int crow = cbase + (reg & 3) + 8 * (reg >> 2);
            Ob[(size_t)crow * OSP] = acc[j][reg];
        }
    }
}

extern "C" void kernel_launch(void* const* d_in, const int* in_sizes, int n_in,
                              void* d_out, int out_size, void* d_ws, size_t ws_size,
                              hipStream_t stream) {
    const float* X  = (const float*)d_in[0];
    const float* Kw = (const float*)d_in[1];
    float* Out = (float*)d_out;
    _Float16* A16 = (_Float16*)d_ws;    // 147456 B

    prep_a<<<(COUT * KTOT + 255) / 256, 256, 0, stream>>>(Kw, A16);
    // probes first (outputs overwritten by the final correct dispatch)
    conv_abl<0><<<SPTOT / 128, 512, 0, stream>>>(X, A16, Out);  // drain-free barrier
    conv_abl<1><<<SPTOT / 128, 512, 0, stream>>>(X, A16, Out);  // L2-hot gathers
    conv_abl<2><<<SPTOT / 128, 512, 0, stream>>>(X, A16, Out);  // v7 correct (final)
}

// Round 16
// 114.413 us; speedup vs baseline: 2.9926x; 2.9926x over previous
//
#include <hip/hip_runtime.h>

// Conv2d 3x3 VALID (NCHW/OIHW, fp32), fp16 MFMA, v10 = v7 + drain-free barrier.
// Ablation r15: MODE0 (lgkmcnt(0)-only waitcnt + raw s_barrier, via BUILTINS --
// no asm "memory" clobber, so regalloc stays intact) ran ~95us vs 117 baseline;
// L2-hot-gather probe was neutral -> the __syncthreads vmcnt(0) drain was the
// exposed latency. Global loads stay in flight across the barrier and are
// consumed same-wave through compiler-counted vmcnt waits; LDS ordering (the
// only cross-wave hazard) is fully covered by lgkmcnt(0) before s_barrier.

typedef __attribute__((ext_vector_type(8)))  _Float16 f16x8;
typedef __attribute__((ext_vector_type(16))) float    f32x16;

struct __attribute__((aligned(4))) f2u { float x, y; };

constexpr int C_IN = 64, H = 112, W = 112;
constexpr int COUT = 128, OH = 110, OW = 110;
constexpr int NIMG = 32;
constexpr int KTOT = C_IN * 9;            // 576
constexpr int OSP  = OH * OW;             // 12100
constexpr int SPTOT = NIMG * OSP;         // 387200 = 3025*128
constexpr int IMG_STRIDE = C_IN * H * W;
constexpr int CH_STRIDE  = H * W;         // 12544
constexpr int LDC = 72;                   // hw per sp-row (144B, 16B-aligned)

__device__ __forceinline__ uint pkrtz_u32(float lo, float hi) {
    union { __fp16 __attribute__((ext_vector_type(2))) h; uint u; } c;
    c.h = __builtin_amdgcn_cvt_pkrtz(lo, hi);
    return c.u;
}

// column-swizzled LDS halfword index (in-row bijective, bank-balanced)
__device__ __forceinline__ int swz(int row, int chw) {
    return row * LDC + (chw ^ (((row >> 1) & 7) << 3));
}

// LDS-ordering barrier WITHOUT the vmcnt(0) drain (builtins, no asm clobber):
// waitcnt imm 0xC07F = vmcnt(63) | expcnt(7) | lgkmcnt(0)  -> waits LDS only.
#define BAR()                                        \
    {                                                \
        __builtin_amdgcn_s_waitcnt(0xC07F);          \
        __builtin_amdgcn_s_barrier();                \
    }

// A16[((s*8+o)*COUT + cout)*8 + j] = (f16)Kw[cout][(o*8+j)*9 + s]  (v4-verified)
__global__ void prep_a(const float* __restrict__ Kw, _Float16* __restrict__ A16) {
    int idx = blockIdx.x * 256 + threadIdx.x;
    if (idx >= COUT * KTOT) return;
    int cout = idx / KTOT, k = idx - cout * KTOT;
    int c = k / 9, s = k - c * 9;
    int o = c >> 3, j = c & 7;
    A16[((size_t)(s * 8 + o) * COUT + cout) * 8 + j] = (_Float16)Kw[idx];
}

__global__ __launch_bounds__(512, 4)
void conv_v10(const float* __restrict__ X,
              const _Float16* __restrict__ A16,
              float* __restrict__ Out)
{
    __shared__ __align__(16) _Float16 Bs[2][128 * LDC];   // 36864 B

    const int t = threadIdx.x;

    // XCD-bijective block swizzle (m204); nwg=3025
    const int nwg = gridDim.x;
    const int q8 = nwg >> 3, r8 = nwg & 7;
    const int xcd = blockIdx.x & 7, idx8 = blockIdx.x >> 3;
    const int bid = (xcd < r8 ? xcd * (q8 + 1) : r8 * (q8 + 1) + (xcd - r8) * q8) + idx8;
    const int spBase = bid * 128;

    // ---- staging mapping (v4-identical) ----
    const int spp = t & 63;
    const int c0  = (t >> 6) << 3;
    const int sp0 = spBase + 2 * spp;
    const int nimg = sp0 / OSP;
    const int rsp  = sp0 - nimg * OSP;
    const int oh   = rsp / OW;
    const int ow   = rsp - oh * OW;
    const float* Xr = X + ((size_t)nimg * IMG_STRIDE + (size_t)c0 * CH_STRIDE + oh * W + ow);
    const int whw0 = swz(2 * spp,     c0);
    const int whw1 = swz(2 * spp + 1, c0);

    // ---- compute mapping (v4-identical): 8 waves = 4 cout-q x 2 sp-halves ----
    const int lane  = t & 63;
    const int wv    = t >> 6;
    const int wq    = wv >> 1;
    const int wc    = wv & 1;
    const int frow  = lane & 31;
    const int khalf = lane >> 5;
    const size_t arow = (size_t)(wq * 32 + frow) * 8;
    const int bmask = ((frow >> 1) & 7) << 3;
    const int brw0  = (wc * 64 + frow) * LDC;
    const int brw1  = (wc * 64 + 32 + frow) * LDC;

    f32x16 acc[2];
#pragma unroll
    for (int j = 0; j < 2; j++)
#pragma unroll
        for (int e = 0; e < 16; e++) acc[j][e] = 0.f;

    f2u g[8];
    f16x8 aA[4], aB[4];

#define SOFF(S) (((S) / 3) * W + ((S) % 3))

#define GATHER(S)                                                              \
    {                                                                          \
        _Pragma("unroll")                                                      \
        for (int j = 0; j < 8; j++)                                            \
            g[j] = *reinterpret_cast<const f2u*>(Xr + (size_t)j * CH_STRIDE + SOFF(S)); \
    }

#define CVTWRITE(BUF)                                                          \
    {                                                                          \
        union { uint u[4]; f16x8 v; } px, py;                                  \
        _Pragma("unroll")                                                      \
        for (int p = 0; p < 4; p++) {                                          \
            px.u[p] = pkrtz_u32(g[2 * p].x, g[2 * p + 1].x);                   \
            py.u[p] = pkrtz_u32(g[2 * p].y, g[2 * p + 1].y);                   \
        }                                                                      \
        *reinterpret_cast<f16x8*>(&Bs[BUF][whw0]) = px.v;                      \
        *reinterpret_cast<f16x8*>(&Bs[BUF][whw1]) = py.v;                      \
    }

#define ALOAD(DST, S)                                                          \
    {                                                                          \
        _Pragma("unroll")                                                      \
        for (int kk = 0; kk < 4; kk++)                                         \
            DST[kk] = *reinterpret_cast<const f16x8*>(                         \
                &A16[(size_t)(((S) * 8 + kk * 2 + khalf) * COUT) * 8 + arow]); \
    }

#define MFMA_STEP(B, AREG)                                                     \
    {                                                                          \
        _Pragma("unroll")                                                      \
        for (int kk = 0; kk < 4; kk++) {                                       \
            const int chw = (kk * 16 + khalf * 8) ^ bmask;                     \
            f16x8 b0 = *reinterpret_cast<const f16x8*>(&Bs[B][brw0 + chw]);    \
            f16x8 b1 = *reinterpret_cast<const f16x8*>(&Bs[B][brw1 + chw]);    \
            acc[0] = __builtin_amdgcn_mfma_f32_32x32x16_f16(AREG[kk], b0, acc[0], 0, 0, 0); \
            acc[1] = __builtin_amdgcn_mfma_f32_32x32x16_f16(AREG[kk], b1, acc[1], 0, 0, 0); \
        }                                                                      \
    }

    // one step (compile-time S): issue A(s+1), write B(s+1), issue gather(s+2),
    // MFMA(s), then lgkm-only barrier (globals stay in flight).
#define STEP(S, CUR, NXT)                                                      \
    {                                                                          \
        ALOAD(NXT, (S) + 1);                                                   \
        CVTWRITE(((S) + 1) & 1);                                               \
        if ((S) < 7) GATHER((S) + 2);                                          \
        MFMA_STEP((S) & 1, CUR);                                               \
        BAR();                                                                 \
    }

    // ---- prologue: regs <- A(0); buf0 <- shift0; g <- shift1 ----
    ALOAD(aA, 0);
    GATHER(0);
    CVTWRITE(0);
    GATHER(1);
    BAR();

    STEP(0, aA, aB);
    STEP(1, aB, aA);
    STEP(2, aA, aB);
    STEP(3, aB, aA);
    STEP(4, aA, aB);
    STEP(5, aB, aA);
    STEP(6, aA, aB);
    STEP(7, aB, aA);
    MFMA_STEP(0, aA);   // s=8: Bs[0] holds shift 8

#undef GATHER
#undef CVTWRITE
#undef ALOAD
#undef MFMA_STEP
#undef STEP
#undef SOFF

    // ---- store (v3-verified): D col=frow(sp), cout row=(reg&3)+8*(reg>>2)+4*khalf ----
#pragma unroll
    for (int j = 0; j < 2; j++) {
        const int sp2 = spBase + wc * 64 + j * 32 + frow;
        const int n2  = sp2 / OSP;
        const int r2  = sp2 - n2 * OSP;
        float* Ob = Out + (size_t)n2 * (COUT * (size_t)OSP) + r2;
        const int cbase = wq * 32 + 4 * khalf;
#pragma unroll
        for (int reg = 0; reg < 16; reg++) {
            const int crow = cbase + (reg & 3) + 8 * (reg >> 2);
            Ob[(size_t)crow * OSP] = acc[j][reg];
        }
    }
}

extern "C" void kernel_launch(void* const* d_in, const int* in_sizes, int n_in,
                              void* d_out, int out_size, void* d_ws, size_t ws_size,
                              hipStream_t stream) {
    const float* X  = (const float*)d_in[0];
    const float* Kw = (const float*)d_in[1];
    float* Out = (float*)d_out;
    _Float16* A16 = (_Float16*)d_ws;    // 147456 B

    prep_a<<<(COUT * KTOT + 255) / 256, 256, 0, stream>>>(Kw, A16);
    conv_v10<<<SPTOT / 128, 512, 0, stream>>>(X, A16, Out);
}